// Round 3
// baseline (374.204 us; speedup 1.0000x reference)
//
#include <hip/hip_runtime.h>
#include <hip/hip_bf16.h>

#define MAX_DIST 32.0f
#define BOX 129
#define BOX3 (129 * 129 * 129)

// ---- Pass 2: build per-cell linked lists of point indices. ----
__global__ void __launch_bounds__(256) build_lists_kernel(
    const float* __restrict__ coords,
    int* __restrict__ head,
    int* __restrict__ next,
    int N) {
  int stride = gridDim.x * blockDim.x;
  for (int p = blockIdx.x * blockDim.x + threadIdx.x; p < N; p += stride) {
    float x = coords[3 * p + 0];
    float y = coords[3 * p + 1];
    float z = coords[3 * p + 2];
    // (c + 32) / 0.5 == (c + 32) * 2 (exact); round-half-even matches jnp.round
    int gx = __float2int_rn((x + MAX_DIST) * 2.0f);
    int gy = __float2int_rn((y + MAX_DIST) * 2.0f);
    int gz = __float2int_rn((z + MAX_DIST) * 2.0f);
    if ((unsigned)gx < BOX && (unsigned)gy < BOX && (unsigned)gz < BOX) {
      int cell = (gx * BOX + gy) * BOX + gz;
      next[p] = atomicExch(&head[cell], p);
    }
  }
}

// ---- Pass 3: one 8-lane group per cell gathers its point list. ----
// Each cell's 32 features = 8 float4 fragments; lane fp owns fragment fp.
// head/next loads are same-address within the group (broadcast); feature
// reads are 128B coalesced per point; output is one plain, fully-coalesced
// 128B store per cell. No grid atomics, no 275MB pre-zero.
__global__ void __launch_bounds__(256) gather_kernel(
    const int* __restrict__ head,
    const int* __restrict__ next,
    const float4* __restrict__ feats4,
    float4* __restrict__ grid4) {
  long t = (long)blockIdx.x * blockDim.x + threadIdx.x;
  if (t >= (long)BOX3 * 8) return;
  int cell = (int)(t >> 3);
  int fp = (int)(t & 7);
  float4 acc = make_float4(0.f, 0.f, 0.f, 0.f);
  int p = head[cell];
  while (p >= 0) {
    float4 v = feats4[(long)p * 8 + fp];
    acc.x += v.x; acc.y += v.y; acc.z += v.z; acc.w += v.w;
    p = next[p];
  }
  grid4[t] = acc;
}

// ---- Fallback (round-1 proven path) if workspace is too small. ----
__global__ void __launch_bounds__(256) scatter_fallback_kernel(
    const float* __restrict__ coords,
    const float2* __restrict__ feats,
    float* __restrict__ grid,
    int N) {
  int total = N * 16;
  int stride = gridDim.x * blockDim.x;
  for (int t = blockIdx.x * blockDim.x + threadIdx.x; t < total; t += stride) {
    int p = t >> 4;
    int fp = t & 15;
    float x = coords[3 * p + 0];
    float y = coords[3 * p + 1];
    float z = coords[3 * p + 2];
    int gx = __float2int_rn((x + MAX_DIST) * 2.0f);
    int gy = __float2int_rn((y + MAX_DIST) * 2.0f);
    int gz = __float2int_rn((z + MAX_DIST) * 2.0f);
    if ((unsigned)gx < BOX && (unsigned)gy < BOX && (unsigned)gz < BOX) {
      float2 v = feats[(long)p * 16 + fp];
      long base = (((long)gx * BOX + gy) * BOX + gz) * 32 + 2 * fp;
      atomicAdd(&grid[base + 0], v.x);
      atomicAdd(&grid[base + 1], v.y);
    }
  }
}

extern "C" void kernel_launch(void* const* d_in, const int* in_sizes, int n_in,
                              void* d_out, int out_size, void* d_ws, size_t ws_size,
                              hipStream_t stream) {
  const float* coords = (const float*)d_in[0];
  int N = in_sizes[0] / 3;  // 500000

  size_t head_bytes = (size_t)BOX3 * sizeof(int);              // 8,586,756
  size_t head_pad   = (head_bytes + 255) & ~(size_t)255;       // 256B-align
  size_t needed     = head_pad + (size_t)N * sizeof(int);

  if (ws_size >= needed) {
    int* head = (int*)d_ws;
    int* next = (int*)((char*)d_ws + head_pad);

    // head = -1 sentinels (d_ws is poisoned 0xAA every call).
    hipMemsetAsync(head, 0xFF, head_bytes, stream);

    int blocks2 = (N + 255) / 256;
    build_lists_kernel<<<blocks2, 256, 0, stream>>>(coords, head, next, N);

    long total3 = (long)BOX3 * 8;
    int blocks3 = (int)((total3 + 255) / 256);
    gather_kernel<<<blocks3, 256, 0, stream>>>(
        head, next, (const float4*)d_in[1], (float4*)d_out);
  } else {
    // Proven round-1 path.
    hipMemsetAsync(d_out, 0, (size_t)out_size * sizeof(float), stream);
    int total = N * 16;
    int blocks = 4096;
    if (blocks > (total + 255) / 256) blocks = (total + 255) / 256;
    scatter_fallback_kernel<<<blocks, 256, 0, stream>>>(
        coords, (const float2*)d_in[1], (float*)d_out, N);
  }
}